// Round 5
// baseline (249.949 us; speedup 1.0000x reference)
//
#include <hip/hip_runtime.h>

// DisMaxLossFirstPart: logits = -|ds|*(dist + mean_c(dist)) / temp
// dist[b,c] = sqrt(max(1 - <fn_b, pn_c>, 0)), fn/pn L2-normalized rows.
// B=32768, C=1000, F=256. fp32 in/out; bf16 MFMA internally.
//
// Round 5: 512-thread blocks (8 waves), 32 feature rows per block, each wave
// owns 128 classes (8 tiles of 16). Each prototype fragment load feeds TWO
// independent MFMA chains (row-groups 0-15 / 16-31): halves the L2 prototype
// stream (1 GB -> 512 MB) and doubles MFMA ILP per load. VGPR capped at 128
// via __launch_bounds__(512,4) -> 2 blocks/CU (16 waves) resident.

typedef __attribute__((ext_vector_type(8))) short short8;
typedef __attribute__((ext_vector_type(4))) float f32x4;
typedef __fp16 h2 __attribute__((ext_vector_type(2)));   // matches cvt_pkrtz return

union U16 { uint4 u4; short8 s8; };

static __device__ __forceinline__ unsigned short f2bf(float x){
  union { float f; unsigned u; } v; v.f = x;
  unsigned r = v.u + 0x7fffu + ((v.u >> 16) & 1u);   // RNE
  return (unsigned short)(r >> 16);
}

#define CPAD 1024          // prototype rows padded to 1024

// Normalize prototypes [C x 256] fp32 -> bf16 in fragment-ready permuted
// layout: 16B chunk index t*512 + s*64 + quad*16 + l16 holds
// pn[t*16 + l16][quad*8 + s*32 .. +8]. Rows >= C written as zeros.
__global__ void norm_protos_kernel(const float* __restrict__ src,
                                   unsigned short* __restrict__ dst, int C)
{
  const int wave = threadIdx.x >> 6;
  const int lane = threadIdx.x & 63;
  const int row  = blockIdx.x * 4 + wave;     // 0..1023
  const int t    = row >> 4;
  const int l16  = row & 15;
  const int s    = lane >> 3;                 // element e=4l: s = e>>5
  const int quad = (lane >> 1) & 3;           // quad = (e>>3)&3
  const int j    = (lane & 1) * 4;            // j = e&7 in {0,4}

  ushort4 o = {0, 0, 0, 0};
  if (row < C){
    const float4 v = *(const float4*)(src + row * 256 + lane * 4);
    float ss = v.x*v.x + v.y*v.y + v.z*v.z + v.w*v.w;
    #pragma unroll
    for (int off = 32; off; off >>= 1) ss += __shfl_xor(ss, off);
    const float inv = 1.0f / fmaxf(sqrtf(ss), 1e-12f);
    o.x = f2bf(v.x * inv); o.y = f2bf(v.y * inv);
    o.z = f2bf(v.z * inv); o.w = f2bf(v.w * inv);
  }
  *(ushort4*)(dst + ((size_t)(t*512 + s*64 + quad*16 + l16))*8 + j) = o;
}

__global__ __launch_bounds__(512, 4)
void fused_kernel(const float* __restrict__ feats,
                  const unsigned short* __restrict__ pnw,
                  const float* __restrict__ ds,
                  const float* __restrict__ temp,
                  float* __restrict__ out, int C)
{
  __shared__ float wsum[8][32];   // [wave][block-row]

  const int tid  = threadIdx.x;
  const int wave = tid >> 6;      // 0..7
  const int lane = tid & 63;
  const int quad = lane >> 4;
  const int l16  = lane & 15;
  const long rowbase = (long)blockIdx.x * 32;

  // ---- Phase 0: B-fragments (features) for 2 row-groups, norm fused ----
  // ffrag[g][s] = bf16( fn[rowbase + g*16 + l16][quad*8 + s*32 .. +8] )
  short8 ffrag[2][8];
  #pragma unroll
  for (int g = 0; g < 2; ++g){
    const float* rp = feats + (rowbase + g*16 + l16) * 256 + quad*8;
    float4 va[8], vb[8];
    float ss = 0.f;
    #pragma unroll
    for (int s = 0; s < 8; ++s){
      va[s] = *(const float4*)(rp + s*32);
      vb[s] = *(const float4*)(rp + s*32 + 4);
      ss += va[s].x*va[s].x + va[s].y*va[s].y + va[s].z*va[s].z + va[s].w*va[s].w;
      ss += vb[s].x*vb[s].x + vb[s].y*vb[s].y + vb[s].z*vb[s].z + vb[s].w*vb[s].w;
    }
    ss += __shfl_xor(ss, 16);
    ss += __shfl_xor(ss, 32);
    const float inv = __builtin_amdgcn_rcpf(__builtin_amdgcn_sqrtf(fmaxf(ss, 1e-24f)));
    #pragma unroll
    for (int s = 0; s < 8; ++s){
      U16 u;
      u.u4.x = (unsigned)f2bf(va[s].x*inv) | ((unsigned)f2bf(va[s].y*inv) << 16);
      u.u4.y = (unsigned)f2bf(va[s].z*inv) | ((unsigned)f2bf(va[s].w*inv) << 16);
      u.u4.z = (unsigned)f2bf(vb[s].x*inv) | ((unsigned)f2bf(vb[s].y*inv) << 16);
      u.u4.w = (unsigned)f2bf(vb[s].z*inv) | ((unsigned)f2bf(vb[s].w*inv) << 16);
      ffrag[g][s] = u.s8;
    }
  }

  // ---- GEMM pass: wave owns classes [wave*128, +128) in 8 tiles of 16 ----
  const uint4* tp = (const uint4*)pnw + (size_t)(wave*8)*512 + lane;

  h2 dd[2][8][2];     // per-lane dist strip: 2 row-groups x 8 tiles x 4 classes
  float rsum0 = 0.f, rsum1 = 0.f;

  #pragma unroll
  for (int wt = 0; wt < 8; ++wt){
    const uint4* bp = tp + (size_t)wt*512;
    short8 pfrag[8];
    #pragma unroll
    for (int s = 0; s < 8; ++s){ U16 u; u.u4 = bp[s*64]; pfrag[s] = u.s8; }

    f32x4 acc0 = (f32x4){0.f,0.f,0.f,0.f};
    f32x4 acc1 = (f32x4){0.f,0.f,0.f,0.f};
    #pragma unroll
    for (int s = 0; s < 8; ++s){
      acc0 = __builtin_amdgcn_mfma_f32_16x16x32_bf16(pfrag[s], ffrag[0][s], acc0, 0, 0, 0);
      acc1 = __builtin_amdgcn_mfma_f32_16x16x32_bf16(pfrag[s], ffrag[1][s], acc1, 0, 0, 0);
    }

    const int cls = wave*128 + wt*16 + quad*4;   // C%4==0: group all-or-nothing
    const bool valid = cls < C;

    float a0 = __builtin_amdgcn_sqrtf(fmaxf(1.0f - acc0[0], 0.0f));
    float a1 = __builtin_amdgcn_sqrtf(fmaxf(1.0f - acc0[1], 0.0f));
    float a2 = __builtin_amdgcn_sqrtf(fmaxf(1.0f - acc0[2], 0.0f));
    float a3 = __builtin_amdgcn_sqrtf(fmaxf(1.0f - acc0[3], 0.0f));
    float b0 = __builtin_amdgcn_sqrtf(fmaxf(1.0f - acc1[0], 0.0f));
    float b1 = __builtin_amdgcn_sqrtf(fmaxf(1.0f - acc1[1], 0.0f));
    float b2 = __builtin_amdgcn_sqrtf(fmaxf(1.0f - acc1[2], 0.0f));
    float b3 = __builtin_amdgcn_sqrtf(fmaxf(1.0f - acc1[3], 0.0f));

    rsum0 += valid ? (a0 + a1 + a2 + a3) : 0.0f;
    rsum1 += valid ? (b0 + b1 + b2 + b3) : 0.0f;

    dd[0][wt][0] = __builtin_amdgcn_cvt_pkrtz(a0, a1);
    dd[0][wt][1] = __builtin_amdgcn_cvt_pkrtz(a2, a3);
    dd[1][wt][0] = __builtin_amdgcn_cvt_pkrtz(b0, b1);
    dd[1][wt][1] = __builtin_amdgcn_cvt_pkrtz(b2, b3);
  }

  // ---- Row means: reduce over quads in-wave, exchange across 8 waves ----
  rsum0 += __shfl_xor(rsum0, 16);
  rsum0 += __shfl_xor(rsum0, 32);
  rsum1 += __shfl_xor(rsum1, 16);
  rsum1 += __shfl_xor(rsum1, 32);
  if (quad == 0){
    wsum[wave][l16]      = rsum0;
    wsum[wave][16 + l16] = rsum1;
  }
  __syncthreads();

  const float invC = 1.0f / (float)C;
  float mean0 = 0.f, mean1 = 0.f;
  #pragma unroll
  for (int w = 0; w < 8; ++w){
    mean0 += wsum[w][l16];
    mean1 += wsum[w][16 + l16];
  }
  mean0 *= invC; mean1 *= invC;

  const float nscale = -fabsf(ds[0]) / temp[0];
  const float bias0 = nscale * mean0;
  const float bias1 = nscale * mean1;

  // ---- Epilogue: coalesced float4 stores ----
  float* orow0 = out + (rowbase + l16) * (size_t)C;
  float* orow1 = out + (rowbase + 16 + l16) * (size_t)C;
  #pragma unroll
  for (int wt = 0; wt < 8; ++wt){
    const int cls = wave*128 + wt*16 + quad*4;
    if (cls < C){
      float4 o;
      o.x = fmaf(nscale, (float)dd[0][wt][0][0], bias0);
      o.y = fmaf(nscale, (float)dd[0][wt][0][1], bias0);
      o.z = fmaf(nscale, (float)dd[0][wt][1][0], bias0);
      o.w = fmaf(nscale, (float)dd[0][wt][1][1], bias0);
      *(float4*)(orow0 + cls) = o;
      float4 p;
      p.x = fmaf(nscale, (float)dd[1][wt][0][0], bias1);
      p.y = fmaf(nscale, (float)dd[1][wt][0][1], bias1);
      p.z = fmaf(nscale, (float)dd[1][wt][1][0], bias1);
      p.w = fmaf(nscale, (float)dd[1][wt][1][1], bias1);
      *(float4*)(orow1 + cls) = p;
    }
  }
}

extern "C" void kernel_launch(void* const* d_in, const int* in_sizes, int n_in,
                              void* d_out, int out_size, void* d_ws, size_t ws_size,
                              hipStream_t stream) {
  const float* features = (const float*)d_in[0];
  const float* protos   = (const float*)d_in[1];
  const float* dscale   = (const float*)d_in[2];
  const float* temp     = (const float*)d_in[3];
  float* out = (float*)d_out;

  const int F = 256;
  const int B = in_sizes[0] / F;   // 32768
  const int C = in_sizes[1] / F;   // 1000

  unsigned short* pnw = (unsigned short*)d_ws;   // [1024 x 256] bf16, permuted

  norm_protos_kernel<<<CPAD/4, 256, 0, stream>>>(protos, pnw, C);
  fused_kernel<<<B/32, 512, 0, stream>>>(features, pnw, dscale, temp, out, C);
}